// Round 22
// baseline (63.851 us; speedup 1.0000x reference)
//
#include <hip/hip_runtime.h>

#define B_N 4096
#define M_N 3
#define D_N 256
#define LOG2E 1.44269504088896340736f
#define LN2   0.69314718055994530942f
#define C_OFF   64.0f
#define T_CLAMP 112.0f

typedef __bf16 bf16x8 __attribute__((ext_vector_type(8)));
typedef float  f32x4  __attribute__((ext_vector_type(4)));

__device__ __forceinline__ float bf2f(unsigned short h) {
    return __uint_as_float(((unsigned int)h) << 16);
}

// 8 consecutive f32 -> bf16x8 (RNE via compiler packed cvt)
__device__ __forceinline__ bf16x8 cvt8(const float* __restrict__ p) {
    float4 u0 = *reinterpret_cast<const float4*>(p);
    float4 u1 = *reinterpret_cast<const float4*>(p + 4);
    bf16x8 r;
    r[0] = (__bf16)u0.x; r[1] = (__bf16)u0.y; r[2] = (__bf16)u0.z; r[3] = (__bf16)u0.w;
    r[4] = (__bf16)u1.x; r[5] = (__bf16)u1.y; r[6] = (__bf16)u1.z; r[7] = (__bf16)u1.w;
    return r;
}

// Symmetric-pair main, no atomics, f32 input read DIRECTLY (cvt pass fused in).
// Panels of 128 rows -> 528 pairs (a<=b). Block = one pair: X_a.X_b^T
// (128x128, K=256), 8 phases x 16 cols, dbuf LDS + verified XOR swizzle,
// 4 waves x 32 rows. A-frags: f32 load + cast in prologue. B-staging: f32
// load + cast + same linear ds_write. Diag blocks also emit norm2 (each row's
// 256 bf16 elems live in 4 lanes' afrag -> 128 FMA + 2 shfl, once per (m,i)).
// Row-side -> slot b, col-side (a<b) -> slot a; 32 slots, plain f32 stores.
// launch_bounds(256,3): measured-safe (min-waves=4 caps VGPR at 64 -> spills).
// grid = 3m x 528 = 1584 blocks (6.2/CU).
__global__ __launch_bounds__(256, 3) void main_kernel(
    const float* __restrict__ tokens, const int* __restrict__ labels,
    float2* __restrict__ partials, float* __restrict__ norm2) {
    int raw = blockIdx.x;
    int bid = (raw & 7) * 198 + (raw >> 3);  // bijective XCD swizzle (1584 = 8*198)
    int m    = bid / 528;
    int beta = bid - m * 528;
    int b = 0;                                // triangular decode
    while ((b + 1) * (b + 2) / 2 <= beta) ++b;
    int a = beta - (b * (b + 1)) / 2;         // 0 <= a <= b <= 31
    bool offd = (a != b);
    int cb = b * 128;

    int tid  = threadIdx.x;
    int wave = tid >> 6, lane = tid & 63;
    int lr = lane & 15, lk = lane >> 4;

    __shared__ __align__(16) char ldsB[2][8192];
    __shared__ int labl[128];
    __shared__ float colbuf[4][8][16][2];
    if (tid < 128) labl[tid] = labels[cb + tid];

    // A fragments: rows r0 + rt*16 + lr (panel a); f32 load + cast, whole kernel
    int r0 = a * 128 + wave * 32;
    bf16x8 afrag[2][8];
#pragma unroll
    for (int rt = 0; rt < 2; ++rt) {
        const float* rp = tokens + ((size_t)(r0 + rt * 16 + lr) * 3 + m) * 256 + lk * 8;
#pragma unroll
        for (int kf = 0; kf < 8; ++kf)
            afrag[rt][kf] = cvt8(rp + kf * 32);
    }
    int labr[2][4];
#pragma unroll
    for (int rt = 0; rt < 2; ++rt)
#pragma unroll
        for (int j = 0; j < 4; ++j)
            labr[rt][j] = labels[r0 + rt * 16 + lk * 4 + j];

    // diag blocks emit norm2 (sum of bf16(x)^2, matching the MFMA's operands)
    if (!offd) {
#pragma unroll
        for (int rt = 0; rt < 2; ++rt) {
            float nrm = 0.f;
#pragma unroll
            for (int kf = 0; kf < 8; ++kf)
#pragma unroll
                for (int e = 0; e < 8; ++e) {
                    float x = (float)afrag[rt][kf][e];
                    nrm = fmaf(x, x, nrm);
                }
            nrm += __shfl_xor(nrm, 16);
            nrm += __shfl_xor(nrm, 32);
            if (lk == 0) norm2[m * B_N + r0 + rt * 16 + lr] = nrm;
        }
    }

    float S[2][4] = {{0.f, 0.f, 0.f, 0.f}, {0.f, 0.f, 0.f, 0.f}};
    float P[2][4] = {{0.f, 0.f, 0.f, 0.f}, {0.f, 0.f, 0.f, 0.f}};

    // Staging map (involution verified r4-r21; cb%8==0): thread (lc=tid>>5,
    // w=tid&31) loads source chunk w^(lc&7) of cols (cb+lc),(cb+lc+8) from f32
    // tokens, casts, writes LDS linearly at tid*16 / 4096+tid*16. Reads apply
    // the same XOR. Column step per phase: 16 rows x 768 f32 = 12288.
    int lc  = tid >> 5;
    int w   = tid & 31;
    int sch = w ^ (lc & 7);
    const float* sb0 = tokens + ((size_t)(cb + lc) * 3 + m) * 256 + sch * 8;
    const float* sb1 = sb0 + 8 * 768;   // col cb+lc+8

    // prologue: tile 0 -> buf0
    {
        bf16x8 t0 = cvt8(sb0);
        bf16x8 t1 = cvt8(sb1);
        *reinterpret_cast<bf16x8*>(&ldsB[0][tid * 16])        = t0;
        *reinterpret_cast<bf16x8*>(&ldsB[0][4096 + tid * 16]) = t1;
    }

    for (int kb = 0; kb < 8; ++kb) {
        int cur = kb & 1;
        __syncthreads();   // buf[cur] staged; prior reads of buf[cur^1] drained

        int nkb = (kb + 1) & 7;    // wrap: last-iter load/write dead but safe
        bf16x8 nt0 = cvt8(sb0 + (size_t)nkb * 12288);
        bf16x8 nt1 = cvt8(sb1 + (size_t)nkb * 12288);

        const char* bp = ldsB[cur];
        int swz = (lr & 7) << 4;
        bf16x8 bfrag[8];
#pragma unroll
        for (int kf = 0; kf < 8; ++kf)
            bfrag[kf] = *reinterpret_cast<const bf16x8*>(
                bp + lr * 512 + (((kf * 4 + lk) << 4) ^ swz));
        int labc = labl[kb * 16 + lr];

        f32x4 acc0 = {0.f, 0.f, 0.f, 0.f};
        f32x4 acc1 = {0.f, 0.f, 0.f, 0.f};
#pragma unroll
        for (int kf = 0; kf < 8; ++kf) {
            acc0 = __builtin_amdgcn_mfma_f32_16x16x32_bf16(afrag[0][kf], bfrag[kf], acc0, 0, 0, 0);
            acc1 = __builtin_amdgcn_mfma_f32_16x16x32_bf16(afrag[1][kf], bfrag[kf], acc1, 0, 0, 0);
        }

        float cs = 0.f, cp = 0.f;
        int cg0 = cb + kb * 16;
        if ((cg0 < r0 + 32) && (cg0 + 16 > r0)) {   // only in diag blocks (a==b)
            int colg = cg0 + lr;
#pragma unroll
            for (int rt = 0; rt < 2; ++rt) {
                f32x4 aa = rt ? acc1 : acc0;
#pragma unroll
                for (int j = 0; j < 4; ++j) {
                    float s2 = aa[j];
                    float t = fminf(fmaf(s2, LOG2E, -C_OFF), T_CLAMP);
                    float e = __builtin_amdgcn_exp2f(t);
                    int row = r0 + rt * 16 + lk * 4 + j;
                    e = (colg == row) ? 0.f : e;    // exclude self from partition
                    bool mt = (labc == labr[rt][j]);
                    S[rt][j] += e;  P[rt][j] += mt ? s2 : 0.f;
                    cs += e;        cp += mt ? s2 : 0.f;
                }
            }
        } else {
#pragma unroll
            for (int rt = 0; rt < 2; ++rt) {
                f32x4 aa = rt ? acc1 : acc0;
#pragma unroll
                for (int j = 0; j < 4; ++j) {
                    float s2 = aa[j];
                    float t = fminf(fmaf(s2, LOG2E, -C_OFF), T_CLAMP);
                    float e = __builtin_amdgcn_exp2f(t);
                    bool mt = (labc == labr[rt][j]);
                    S[rt][j] += e;  P[rt][j] += mt ? s2 : 0.f;
                    cs += e;        cp += mt ? s2 : 0.f;
                }
            }
        }

        // col-side: sum over the wave's 32 rows (lanes lr, lr+16, lr+32, lr+48)
        cs += __shfl_xor(cs, 16); cs += __shfl_xor(cs, 32);
        cp += __shfl_xor(cp, 16); cp += __shfl_xor(cp, 32);
        if (lk == 0) { colbuf[wave][kb][lr][0] = cs; colbuf[wave][kb][lr][1] = cp; }

        // write next tile (other buffer); barrier at loop top publishes it
        char* dst = (char*)ldsB[cur ^ 1];
        *reinterpret_cast<bf16x8*>(dst + tid * 16)        = nt0;
        *reinterpret_cast<bf16x8*>(dst + 4096 + tid * 16) = nt1;
    }

    __syncthreads();   // colbuf complete

    // row-side flush: reduce over 16 col-lanes, store to slot b
#pragma unroll
    for (int rt = 0; rt < 2; ++rt)
#pragma unroll
        for (int j = 0; j < 4; ++j) {
            float sv = S[rt][j], pv = P[rt][j];
#pragma unroll
            for (int msk = 1; msk < 16; msk <<= 1) {
                sv += __shfl_xor(sv, msk);
                pv += __shfl_xor(pv, msk);
            }
            if (lr == 0) {
                int row = r0 + rt * 16 + lk * 4 + j;
                float2 q; q.x = sv; q.y = pv;
                partials[(size_t)(b * 3 + m) * B_N + row] = q;
            }
        }

    // col-side flush (off-diag only): sum colbuf over 4 waves, store to slot a
    if (offd && tid < 128) {
        int kb = tid >> 4, cr = tid & 15;
        float sv = colbuf[0][kb][cr][0] + colbuf[1][kb][cr][0]
                 + colbuf[2][kb][cr][0] + colbuf[3][kb][cr][0];
        float pv = colbuf[0][kb][cr][1] + colbuf[1][kb][cr][1]
                 + colbuf[2][kb][cr][1] + colbuf[3][kb][cr][1];
        int col = cb + tid;   // tid == kb*16 + cr
        float2 q; q.x = sv; q.y = pv;
        partials[(size_t)(a * 3 + m) * B_N + col] = q;
    }
}

// one thread per (m,i): merge 32 f32 slot-partials, finish the loss term.
// (r19-proven form: blockpart + nv, separate tiny final kernel)
__global__ void reduce_kernel(const float2* __restrict__ partials,
                              const float* __restrict__ norm2,
                              const int* __restrict__ labels,
                              float* __restrict__ blockpart,
                              int* __restrict__ nvout) {
    __shared__ int h[32];
    int tid = threadIdx.x;
    if (tid < 32) h[tid] = 0;
    __syncthreads();
    for (int i = tid; i < B_N; i += 256) atomicAdd(&h[labels[i]], 1);
    __syncthreads();
    if (blockIdx.x == 0 && tid == 0) {
        int nv = 0;
#pragma unroll
        for (int c = 0; c < 32; ++c) nv += (h[c] >= 2) ? h[c] : 0;
        nvout[0] = nv;
    }
    int gid = blockIdx.x * 256 + tid;   // 12288 = m*4096 + i
    int m = gid >> 12, i = gid & 4095;
    float S = 0.f, P = 0.f;
#pragma unroll
    for (int s = 0; s < 32; ++s) {
        float2 q = partials[(size_t)(s * 3 + m) * B_N + i];
        S += q.x; P += q.y;
    }
    P -= norm2[gid];                       // remove self-sim from positive sum
    int pc = h[labels[i]] - 1;
    float contrib = (pc > 0)
        ? (__builtin_amdgcn_logf(S) + C_OFF) * LN2 - P / (float)pc
        : 0.f;
#pragma unroll
    for (int off = 32; off >= 1; off >>= 1) contrib += __shfl_down(contrib, off);
    __shared__ float w4[4];
    if ((tid & 63) == 0) w4[tid >> 6] = contrib;
    __syncthreads();
    if (tid == 0) blockpart[blockIdx.x] = w4[0] + w4[1] + w4[2] + w4[3];
}

__global__ void final_kernel(const float* __restrict__ blockpart, const int* __restrict__ nv,
                             float* __restrict__ out) {
    int lane = threadIdx.x;
    float s = (lane < 48) ? blockpart[lane] : 0.f;
#pragma unroll
    for (int off = 32; off >= 1; off >>= 1) s += __shfl_down(s, off);
    if (lane == 0) out[0] = s / (float)(nv[0] * M_N);
}

extern "C" void kernel_launch(void* const* d_in, const int* in_sizes, int n_in,
                              void* d_out, int out_size, void* d_ws, size_t ws_size,
                              hipStream_t stream) {
    const float* tokens = (const float*)d_in[0];
    const int*   labels = (const int*)d_in[1];
    float* out = (float*)d_out;

    char* ws = (char*)d_ws;
    int*    nv        = (int*)(ws + 128);                   // 1 int
    float*  blockpart = (float*)(ws + 256);                 // 48 floats
    float*  norm2     = (float*)(ws + 1024);                // 12288 f32, ends 50176
    float2* partials  = (float2*)(ws + 65536);              // 32*3*4096*8B = 3.15 MB

    main_kernel<<<1584, 256, 0, stream>>>(tokens, labels, partials, norm2);
    reduce_kernel<<<48, 256, 0, stream>>>(partials, norm2, labels, blockpart, nv);
    final_kernel<<<1, 64, 0, stream>>>(blockpart, nv, out);
}

// Round 23
// 51.089 us; speedup vs baseline: 1.2498x; 1.2498x over previous
//
#include <hip/hip_runtime.h>

#define B_N 4096
#define M_N 3
#define D_N 256
#define LOG2E 1.44269504088896340736f
#define LN2   0.69314718055994530942f
#define C_OFF   64.0f
#define T_CLAMP 112.0f

typedef __bf16 bf16x8 __attribute__((ext_vector_type(8)));
typedef float  f32x4  __attribute__((ext_vector_type(4)));

__device__ __forceinline__ unsigned short f2bf(float f) {
    unsigned int u = __float_as_uint(f);
    u += 0x7FFFu + ((u >> 16) & 1u);   // round-to-nearest-even
    return (unsigned short)(u >> 16);
}
__device__ __forceinline__ float bf2f(unsigned short h) {
    return __uint_as_float(((unsigned int)h) << 16);
}

// tokens [i][m][d] f32 -> tokb [m][i][d] bf16; norm2[m*B+i] = sum(bf16(x)^2)
__global__ void cvt_kernel(const float* __restrict__ in, unsigned short* __restrict__ out,
                           float* __restrict__ norm2) {
    int idx = blockIdx.x * blockDim.x + threadIdx.x;   // 786432 float4s
    float4 v = reinterpret_cast<const float4*>(in)[idx];
    int i   = idx / 192;            // 192 = M*D/4
    int rem = idx - i * 192;
    int m   = rem >> 6;
    int d4  = rem & 63;
    ushort4 o;
    o.x = f2bf(v.x); o.y = f2bf(v.y); o.z = f2bf(v.z); o.w = f2bf(v.w);
    reinterpret_cast<ushort4*>(out)[((size_t)m * B_N + i) * 64 + d4] = o;
    float nx = bf2f(o.x), ny = bf2f(o.y), nz = bf2f(o.z), nw = bf2f(o.w);
    float s = nx * nx + ny * ny + nz * nz + nw * nw;
#pragma unroll
    for (int msk = 1; msk < 64; msk <<= 1) s += __shfl_xor(s, msk);
    if ((threadIdx.x & 63) == 0) norm2[m * B_N + i] = s;  // wave spans one (i,m) row
}

// Symmetric-pair main, no atomics. Panels of 128 rows -> 528 pairs (a<=b).
// Block = one pair: tile X_a.X_b^T (128x128, K=256), 8 phases x 16 cols,
// dbuf LDS + verified XOR swizzle, 4 waves x 32 rows. Row-side -> slot b,
// col-side (a<b) -> slot a; 32 slots, bijective, plain f32 stores.
// launch_bounds(256,3): measured VGPR 84, NO spill (bound 4 empirically caps
// VGPR at 64 and spills -- r17/r20). The r19-measured best configuration.
// grid = 3m x 528 = 1584 blocks (6.2/CU).
__global__ __launch_bounds__(256, 3) void main_kernel(
    const unsigned short* __restrict__ tokb, const int* __restrict__ labels,
    float2* __restrict__ partials) {
    int raw = blockIdx.x;
    int bid = (raw & 7) * 198 + (raw >> 3);  // bijective XCD swizzle (1584 = 8*198)
    int m    = bid / 528;
    int beta = bid - m * 528;
    int b = 0;                                // triangular decode
    while ((b + 1) * (b + 2) / 2 <= beta) ++b;
    int a = beta - (b * (b + 1)) / 2;         // 0 <= a <= b <= 31
    bool offd = (a != b);
    int cb = b * 128;

    int tid  = threadIdx.x;
    int wave = tid >> 6, lane = tid & 63;
    int lr = lane & 15, lk = lane >> 4;
    const unsigned short* tm = tokb + (size_t)m * (B_N * D_N);

    __shared__ __align__(16) char ldsB[2][8192];
    __shared__ int labl[128];
    __shared__ float colbuf[4][8][16][2];
    if (tid < 128) labl[tid] = labels[cb + tid];

    // A fragments: rows r0 + rt*16 + lr (panel a), registers for whole kernel
    int r0 = a * 128 + wave * 32;
    bf16x8 afrag[2][8];
#pragma unroll
    for (int rt = 0; rt < 2; ++rt) {
        const unsigned short* rp = tm + (size_t)(r0 + rt * 16 + lr) * D_N + lk * 8;
#pragma unroll
        for (int kf = 0; kf < 8; ++kf)
            afrag[rt][kf] = *reinterpret_cast<const bf16x8*>(rp + kf * 32);
    }
    int labr[2][4];
#pragma unroll
    for (int rt = 0; rt < 2; ++rt)
#pragma unroll
        for (int j = 0; j < 4; ++j)
            labr[rt][j] = labels[r0 + rt * 16 + lk * 4 + j];

    float S[2][4] = {{0.f, 0.f, 0.f, 0.f}, {0.f, 0.f, 0.f, 0.f}};
    float P[2][4] = {{0.f, 0.f, 0.f, 0.f}, {0.f, 0.f, 0.f, 0.f}};

    // Staging map (involution verified r4-r19; cb%8==0): thread (lc=tid>>5,
    // w=tid&31) loads source chunk w^(lc&7) of cols (cb+lc),(cb+lc+8); writes
    // LDS linearly at tid*16 / 4096+tid*16. Reads apply the same XOR.
    int lc  = tid >> 5;
    int w   = tid & 31;
    int sch = w ^ (lc & 7);
    const unsigned short* sbase = tm + (size_t)(cb + lc) * D_N + sch * 8;

    // prologue: tile 0 -> buf0
    {
        bf16x8 t0 = *reinterpret_cast<const bf16x8*>(sbase);
        bf16x8 t1 = *reinterpret_cast<const bf16x8*>(sbase + 8 * D_N);
        *reinterpret_cast<bf16x8*>(&ldsB[0][tid * 16])        = t0;
        *reinterpret_cast<bf16x8*>(&ldsB[0][4096 + tid * 16]) = t1;
    }

    for (int kb = 0; kb < 8; ++kb) {
        int cur = kb & 1;
        __syncthreads();   // buf[cur] staged; prior reads of buf[cur^1] drained

        int nkb = (kb + 1) & 7;    // wrap: last-iter load/write dead but safe
        const unsigned short* np = sbase + (size_t)nkb * (16 * D_N);
        bf16x8 nt0 = *reinterpret_cast<const bf16x8*>(np);
        bf16x8 nt1 = *reinterpret_cast<const bf16x8*>(np + 8 * D_N);

        const char* bp = ldsB[cur];
        int swz = (lr & 7) << 4;
        bf16x8 bfrag[8];
#pragma unroll
        for (int kf = 0; kf < 8; ++kf)
            bfrag[kf] = *reinterpret_cast<const bf16x8*>(
                bp + lr * 512 + (((kf * 4 + lk) << 4) ^ swz));
        int labc = labl[kb * 16 + lr];

        f32x4 acc0 = {0.f, 0.f, 0.f, 0.f};
        f32x4 acc1 = {0.f, 0.f, 0.f, 0.f};
#pragma unroll
        for (int kf = 0; kf < 8; ++kf) {
            acc0 = __builtin_amdgcn_mfma_f32_16x16x32_bf16(afrag[0][kf], bfrag[kf], acc0, 0, 0, 0);
            acc1 = __builtin_amdgcn_mfma_f32_16x16x32_bf16(afrag[1][kf], bfrag[kf], acc1, 0, 0, 0);
        }

        float cs = 0.f, cp = 0.f;
        int cg0 = cb + kb * 16;
        if ((cg0 < r0 + 32) && (cg0 + 16 > r0)) {   // only in diag blocks (a==b)
            int colg = cg0 + lr;
#pragma unroll
            for (int rt = 0; rt < 2; ++rt) {
                f32x4 aa = rt ? acc1 : acc0;
#pragma unroll
                for (int j = 0; j < 4; ++j) {
                    float s2 = aa[j];
                    float t = fminf(fmaf(s2, LOG2E, -C_OFF), T_CLAMP);
                    float e = __builtin_amdgcn_exp2f(t);
                    int row = r0 + rt * 16 + lk * 4 + j;
                    e = (colg == row) ? 0.f : e;    // exclude self from partition
                    bool mt = (labc == labr[rt][j]);
                    S[rt][j] += e;  P[rt][j] += mt ? s2 : 0.f;
                    cs += e;        cp += mt ? s2 : 0.f;
                }
            }
        } else {
#pragma unroll
            for (int rt = 0; rt < 2; ++rt) {
                f32x4 aa = rt ? acc1 : acc0;
#pragma unroll
                for (int j = 0; j < 4; ++j) {
                    float s2 = aa[j];
                    float t = fminf(fmaf(s2, LOG2E, -C_OFF), T_CLAMP);
                    float e = __builtin_amdgcn_exp2f(t);
                    bool mt = (labc == labr[rt][j]);
                    S[rt][j] += e;  P[rt][j] += mt ? s2 : 0.f;
                    cs += e;        cp += mt ? s2 : 0.f;
                }
            }
        }

        // col-side: sum over the wave's 32 rows (lanes lr, lr+16, lr+32, lr+48)
        cs += __shfl_xor(cs, 16); cs += __shfl_xor(cs, 32);
        cp += __shfl_xor(cp, 16); cp += __shfl_xor(cp, 32);
        if (lk == 0) { colbuf[wave][kb][lr][0] = cs; colbuf[wave][kb][lr][1] = cp; }

        // write next tile (other buffer); barrier at loop top publishes it
        char* dst = (char*)ldsB[cur ^ 1];
        *reinterpret_cast<bf16x8*>(dst + tid * 16)        = nt0;
        *reinterpret_cast<bf16x8*>(dst + 4096 + tid * 16) = nt1;
    }

    __syncthreads();   // colbuf complete

    // row-side flush: reduce over 16 col-lanes, store to slot b
#pragma unroll
    for (int rt = 0; rt < 2; ++rt)
#pragma unroll
        for (int j = 0; j < 4; ++j) {
            float sv = S[rt][j], pv = P[rt][j];
#pragma unroll
            for (int msk = 1; msk < 16; msk <<= 1) {
                sv += __shfl_xor(sv, msk);
                pv += __shfl_xor(pv, msk);
            }
            if (lr == 0) {
                int row = r0 + rt * 16 + lk * 4 + j;
                float2 q; q.x = sv; q.y = pv;
                partials[(size_t)(b * 3 + m) * B_N + row] = q;
            }
        }

    // col-side flush (off-diag only): sum colbuf over 4 waves, store to slot a
    if (offd && tid < 128) {
        int kb = tid >> 4, cr = tid & 15;
        float sv = colbuf[0][kb][cr][0] + colbuf[1][kb][cr][0]
                 + colbuf[2][kb][cr][0] + colbuf[3][kb][cr][0];
        float pv = colbuf[0][kb][cr][1] + colbuf[1][kb][cr][1]
                 + colbuf[2][kb][cr][1] + colbuf[3][kb][cr][1];
        int col = cb + tid;   // tid == kb*16 + cr
        float2 q; q.x = sv; q.y = pv;
        partials[(size_t)(a * 3 + m) * B_N + col] = q;
    }
}

// one thread per (m,i): merge 32 f32 slot-partials, finish the loss term.
__global__ void reduce_kernel(const float2* __restrict__ partials,
                              const float* __restrict__ norm2,
                              const int* __restrict__ labels,
                              float* __restrict__ blockpart,
                              int* __restrict__ nvout) {
    __shared__ int h[32];
    int tid = threadIdx.x;
    if (tid < 32) h[tid] = 0;
    __syncthreads();
    for (int i = tid; i < B_N; i += 256) atomicAdd(&h[labels[i]], 1);
    __syncthreads();
    if (blockIdx.x == 0 && tid == 0) {
        int nv = 0;
#pragma unroll
        for (int c = 0; c < 32; ++c) nv += (h[c] >= 2) ? h[c] : 0;
        nvout[0] = nv;
    }
    int gid = blockIdx.x * 256 + tid;   // 12288 = m*4096 + i
    int m = gid >> 12, i = gid & 4095;
    float S = 0.f, P = 0.f;
#pragma unroll
    for (int s = 0; s < 32; ++s) {
        float2 q = partials[(size_t)(s * 3 + m) * B_N + i];
        S += q.x; P += q.y;
    }
    P -= norm2[gid];                       // remove self-sim from positive sum
    int pc = h[labels[i]] - 1;
    float contrib = (pc > 0)
        ? (__builtin_amdgcn_logf(S) + C_OFF) * LN2 - P / (float)pc
        : 0.f;
#pragma unroll
    for (int off = 32; off >= 1; off >>= 1) contrib += __shfl_down(contrib, off);
    __shared__ float w4[4];
    if ((tid & 63) == 0) w4[tid >> 6] = contrib;
    __syncthreads();
    if (tid == 0) blockpart[blockIdx.x] = w4[0] + w4[1] + w4[2] + w4[3];
}

__global__ void final_kernel(const float* __restrict__ blockpart, const int* __restrict__ nv,
                             float* __restrict__ out) {
    int lane = threadIdx.x;
    float s = (lane < 48) ? blockpart[lane] : 0.f;
#pragma unroll
    for (int off = 32; off >= 1; off >>= 1) s += __shfl_down(s, off);
    if (lane == 0) out[0] = s / (float)(nv[0] * M_N);
}

extern "C" void kernel_launch(void* const* d_in, const int* in_sizes, int n_in,
                              void* d_out, int out_size, void* d_ws, size_t ws_size,
                              hipStream_t stream) {
    const float* tokens = (const float*)d_in[0];
    const int*   labels = (const int*)d_in[1];
    float* out = (float*)d_out;

    char* ws = (char*)d_ws;
    int*    nv        = (int*)(ws + 128);                   // 1 int
    float*  blockpart = (float*)(ws + 256);                 // 48 floats
    float*  norm2     = (float*)(ws + 1024);                // 12288 f32, ends 50176
    float2* partials  = (float2*)(ws + 65536);              // 32*3*4096*8B = 3.15 MB
    unsigned short* tokb = (unsigned short*)(ws + 3407872); // 6.29 MB, ends 9.7 MB

    cvt_kernel<<<3072, 256, 0, stream>>>(tokens, tokb, norm2);
    main_kernel<<<1584, 256, 0, stream>>>(tokb, labels, partials);
    reduce_kernel<<<48, 256, 0, stream>>>(partials, norm2, labels, blockpart, nv);
    final_kernel<<<1, 64, 0, stream>>>(blockpart, nv, out);
}